// Round 19
// baseline (377.984 us; speedup 1.0000x reference)
//
#include <hip/hip_runtime.h>
#include <math.h>

#define N_NODES 50000
#define N_EDGES 800000
#define IN_FEAT 128
#define HIDDEN 256
#define NUM_GRAPHS 128
#define NUM_CLASSES 10
#define BN_EPS 1e-5f

#define NCHUNK ((N_NODES + 255) / 256)   // 196 scan chunks
#define BINW 512
#define NBINS ((N_NODES + BINW - 1) / BINW)   // 98

typedef __attribute__((ext_vector_type(16))) float f32x16;
typedef __attribute__((ext_vector_type(2))) float f32x2;

__device__ __forceinline__ ushort f2bf(float f) {
    union { float f; uint u; } c; c.f = f;
    uint u = c.u;
    return (ushort)((u + 0x7FFFu + ((u >> 16) & 1u)) >> 16);   // RNE
}
__device__ __forceinline__ float bf2f(ushort h) {
    union { uint u; float f; } c; c.u = ((uint)h) << 16;
    return c.f;
}
// fp8 e4m3 (hardware cvt, OCP on gfx950); matched encode/decode round-trip
__device__ __forceinline__ unsigned char f2fp8(float f) {
    return (unsigned char)(__builtin_amdgcn_cvt_pk_fp8_f32(f, f, 0, false) & 0xFF);
}

// ---------------- CSR build ----------------
__global__ void k_count(const int* __restrict__ dst, int* __restrict__ cnt) {
    int e = blockIdx.x * 256 + threadIdx.x;
    if (e < N_EDGES) atomicAdd(&cnt[dst[e]], 1);
}

// ---- batch histogram: LDS hist, one global atomic per (block, graph) ----
__global__ __launch_bounds__(512) void k_count_batch(const int* __restrict__ batch,
                                                     int* __restrict__ gcnt) {
    __shared__ int hist[NUM_GRAPHS];
    int t = threadIdx.x;
    if (t < NUM_GRAPHS) hist[t] = 0;
    __syncthreads();
    int v = blockIdx.x * 512 + t;
    if (v < N_NODES) atomicAdd(&hist[batch[v]], 1);
    __syncthreads();
    if (t < NUM_GRAPHS && hist[t] > 0) atomicAdd(&gcnt[t], hist[t]);
}

__global__ __launch_bounds__(256) void k_chunksum(const int* __restrict__ cnt,
                                                  int* __restrict__ csum) {
    int i = blockIdx.x * 256 + threadIdx.x;
    int v = (i < N_NODES) ? cnt[i] : 0;
#pragma unroll
    for (int off = 32; off; off >>= 1) v += __shfl_down(v, off, 64);
    __shared__ int ws[4];
    if ((threadIdx.x & 63) == 0) ws[threadIdx.x >> 6] = v;
    __syncthreads();
    if (threadIdx.x == 0) csum[blockIdx.x] = ws[0] + ws[1] + ws[2] + ws[3];
}

// merged scans: block 0 = chunk-offsets scan; block 1 = graph-offsets scan
__global__ __launch_bounds__(256) void k_scan2(const int* __restrict__ csum,
                                               int* __restrict__ choff,
                                               const int* __restrict__ gcnt,
                                               int* __restrict__ goff,
                                               int* __restrict__ gcur) {
    __shared__ int s[256];
    int t = threadIdx.x;
    if (blockIdx.x == 0) {
        int v = (t < NCHUNK) ? csum[t] : 0;
        s[t] = v;
        __syncthreads();
#pragma unroll
        for (int off = 1; off < 256; off <<= 1) {
            int add = (t >= off) ? s[t - off] : 0;
            __syncthreads();
            s[t] += add;
            __syncthreads();
        }
        if (t < NCHUNK) choff[t] = s[t] - v;   // exclusive
    } else {
        int v = (t < NUM_GRAPHS) ? gcnt[t] : 0;
        s[t] = v;
        __syncthreads();
#pragma unroll
        for (int off = 1; off < NUM_GRAPHS; off <<= 1) {
            int add = (t >= off && t < NUM_GRAPHS) ? s[t - off] : 0;
            __syncthreads();
            if (t < NUM_GRAPHS) s[t] += add;
            __syncthreads();
        }
        if (t < NUM_GRAPHS) {
            goff[t] = s[t] - v;
            gcur[t] = s[t] - v;
            if (t == NUM_GRAPHS - 1) goff[NUM_GRAPHS] = s[t];
        }
    }
}

// k_apply also initializes bincur (folded k_initbins)
__global__ __launch_bounds__(256) void k_apply(const int* __restrict__ cnt,
                                               const int* __restrict__ choff,
                                               int* __restrict__ rowp,
                                               float* __restrict__ dinv,
                                               int* __restrict__ bincur) {
    __shared__ int s[256];
    int t = threadIdx.x;
    int i = blockIdx.x * 256 + t;
    int c = (i < N_NODES) ? cnt[i] : 0;
    s[t] = c;
    __syncthreads();
#pragma unroll
    for (int off = 1; off < 256; off <<= 1) {
        int add = (t >= off) ? s[t - off] : 0;
        __syncthreads();
        s[t] += add;
        __syncthreads();
    }
    int incl = s[t];
    int base = choff[blockIdx.x];
    if (i < N_NODES) {
        int ex = base + incl - c;
        rowp[i] = ex;
        dinv[i] = rsqrtf(1.0f + (float)c);
        if ((i & (BINW - 1)) == 0) bincur[i / BINW] = ex;
        if (i == N_NODES - 1) rowp[N_NODES] = base + incl;
    }
}

#define FILLA_EPT 8   // edges per thread; 392 blocks x 2048 edges
__global__ __launch_bounds__(256) void k_binA(const int* __restrict__ src,
                                              const int* __restrict__ dst,
                                              int* __restrict__ bincur,
                                              uint* __restrict__ pairs) {
    __shared__ int hist[NBINS];
    __shared__ int base[NBINS];
    int t = threadIdx.x;
    for (int i = t; i < NBINS; i += 256) hist[i] = 0;
    __syncthreads();
    int e0 = blockIdx.x * (256 * FILLA_EPT);
    int mybin[FILLA_EPT], myoff[FILLA_EPT];
    uint mypair[FILLA_EPT];
#pragma unroll
    for (int j = 0; j < FILLA_EPT; ++j) {
        int e = e0 + j * 256 + t;
        mybin[j] = -1;
        if (e < N_EDGES) {
            int d = dst[e], s = src[e];
            int b = d >> 9;                       // BINW = 512
            mybin[j] = b;
            mypair[j] = (uint)s | ((uint)(d & (BINW - 1)) << 16);
            myoff[j] = atomicAdd(&hist[b], 1);
        }
    }
    __syncthreads();
    for (int i = t; i < NBINS; i += 256)
        base[i] = atomicAdd(&bincur[i], hist[i]);
    __syncthreads();
#pragma unroll
    for (int j = 0; j < FILLA_EPT; ++j) {
        if (mybin[j] >= 0) pairs[base[mybin[j]] + myoff[j]] = mypair[j];
    }
}

// ---- pass B: one block per bin; LDS cursors; writes confined to bin's col region ----
__global__ __launch_bounds__(512) void k_binB(const uint* __restrict__ pairs,
                                              const int* __restrict__ rowp,
                                              int* __restrict__ col) {
    __shared__ int cur[BINW];
    int b = blockIdx.x;
    int v0 = b * BINW;
    int t = threadIdx.x;
    int vend = min(v0 + BINW, N_NODES);
    for (int i = t; i < vend - v0; i += 512) cur[i] = rowp[v0 + i];
    __syncthreads();
    int lo = rowp[v0];
    int hi = rowp[vend];
    for (int i = lo + t; i < hi; i += 512) {
        uint pr = pairs[i];
        int dl = pr >> 16;
        int s = pr & 0xFFFF;
        int slot = atomicAdd(&cur[dl], 1);
        col[slot] = s;
    }
}

// ---- graph bucketing: LDS histogram, one global atomic per (block, graph) ----
__global__ __launch_bounds__(512) void k_fillg(const int* __restrict__ batch,
                                               int* __restrict__ gcur,
                                               int* __restrict__ nlist) {
    __shared__ int hist[NUM_GRAPHS];
    __shared__ int base[NUM_GRAPHS];
    int t = threadIdx.x;
    if (t < NUM_GRAPHS) hist[t] = 0;
    __syncthreads();
    int v = blockIdx.x * 512 + t;
    int g = -1, off = 0;
    if (v < N_NODES) {
        g = batch[v];
        off = atomicAdd(&hist[g], 1);
    }
    __syncthreads();
    if (t < NUM_GRAPHS) base[t] = atomicAdd(&gcur[t], hist[t]);
    __syncthreads();
    if (g >= 0) nlist[base[g] + off] = v;
}

// ---------------- prescale: p0 = fp8(x * dinv[row]) ----------------
__global__ void k_prescale(const float* __restrict__ x, const float* __restrict__ dinv,
                           unsigned char* __restrict__ p0) {
    int i = blockIdx.x * 256 + threadIdx.x;      // per 4 elems
    if (i < N_NODES * IN_FEAT / 4) {
        float4 v = ((const float4*)x)[i];
        float d = dinv[i / (IN_FEAT / 4)];
        uchar4 o;
        o.x = f2fp8(v.x * d); o.y = f2fp8(v.y * d);
        o.z = f2fp8(v.z * d); o.w = f2fp8(v.w * d);
        ((uchar4*)p0)[i] = o;
    }
}

// ---------------- layer-1 aggregation (fp8 in, fp8 out, 8-deep pipeline) ----------------
__global__ __launch_bounds__(256) void k_agg128(const unsigned char* __restrict__ p,
                                                const int* __restrict__ col,
                                                const int* __restrict__ row_ptr,
                                                const float* __restrict__ dinv,
                                                unsigned char* __restrict__ out) {
    const int F = IN_FEAT;
    int wave = threadIdx.x >> 6;
    int lane = threadIdx.x & 63;
    int v = blockIdx.x * 4 + wave;
    if (v >= N_NODES) return;
    int rp0 = row_ptr[v], rp1 = row_ptr[v + 1];
    float d = dinv[v];
    ushort um = ((const ushort*)(p + (size_t)v * F))[lane];
    f32x2 m = __builtin_amdgcn_cvt_pk_f32_fp8((int)um, false);
    float a0 = m.x, a1 = m.y;
    int i = rp0;
    for (; i + 8 <= rp1; i += 8) {
        int s0 = col[i],     s1 = col[i + 1], s2 = col[i + 2], s3 = col[i + 3];
        int s4 = col[i + 4], s5 = col[i + 5], s6 = col[i + 6], s7 = col[i + 7];
        ushort u0 = ((const ushort*)(p + (size_t)s0 * F))[lane];
        ushort u1 = ((const ushort*)(p + (size_t)s1 * F))[lane];
        ushort u2 = ((const ushort*)(p + (size_t)s2 * F))[lane];
        ushort u3 = ((const ushort*)(p + (size_t)s3 * F))[lane];
        ushort u4 = ((const ushort*)(p + (size_t)s4 * F))[lane];
        ushort u5 = ((const ushort*)(p + (size_t)s5 * F))[lane];
        ushort u6 = ((const ushort*)(p + (size_t)s6 * F))[lane];
        ushort u7 = ((const ushort*)(p + (size_t)s7 * F))[lane];
        f32x2 d0 = __builtin_amdgcn_cvt_pk_f32_fp8((int)u0, false);
        f32x2 d1 = __builtin_amdgcn_cvt_pk_f32_fp8((int)u1, false);
        f32x2 d2 = __builtin_amdgcn_cvt_pk_f32_fp8((int)u2, false);
        f32x2 d3 = __builtin_amdgcn_cvt_pk_f32_fp8((int)u3, false);
        f32x2 d4 = __builtin_amdgcn_cvt_pk_f32_fp8((int)u4, false);
        f32x2 d5 = __builtin_amdgcn_cvt_pk_f32_fp8((int)u5, false);
        f32x2 d6 = __builtin_amdgcn_cvt_pk_f32_fp8((int)u6, false);
        f32x2 d7 = __builtin_amdgcn_cvt_pk_f32_fp8((int)u7, false);
        a0 += d0.x + d1.x + d2.x + d3.x + d4.x + d5.x + d6.x + d7.x;
        a1 += d0.y + d1.y + d2.y + d3.y + d4.y + d5.y + d6.y + d7.y;
    }
    for (; i < rp1; ++i) {
        int s = col[i];
        ushort u = ((const ushort*)(p + (size_t)s * F))[lane];
        f32x2 dv = __builtin_amdgcn_cvt_pk_f32_fp8((int)u, false);
        a0 += dv.x; a1 += dv.y;
    }
    uchar2 o;
    o.x = f2fp8(a0 * d); o.y = f2fp8(a1 * d);
    ((uchar2*)(out + (size_t)v * F))[lane] = o;
}

// ---------------- hidden-layer aggregation (fp8 in, fp8 out, 8-deep pipeline) ----------------
__global__ __launch_bounds__(256) void k_agg8(const unsigned char* __restrict__ p,
                                              const int* __restrict__ col,
                                              const int* __restrict__ row_ptr,
                                              const float* __restrict__ dinv,
                                              unsigned char* __restrict__ out) {
    const int F = HIDDEN;
    int wave = threadIdx.x >> 6;
    int lane = threadIdx.x & 63;
    int v = blockIdx.x * 4 + wave;
    if (v >= N_NODES) return;
    int rp0 = row_ptr[v], rp1 = row_ptr[v + 1];
    float d = dinv[v];
    uint um = ((const uint*)(p + (size_t)v * F))[lane];
    f32x2 mlo = __builtin_amdgcn_cvt_pk_f32_fp8((int)um, false);
    f32x2 mhi = __builtin_amdgcn_cvt_pk_f32_fp8((int)um, true);
    float a0 = mlo.x, a1 = mlo.y, a2 = mhi.x, a3 = mhi.y;
    int i = rp0;
    for (; i + 8 <= rp1; i += 8) {
        int s0 = col[i],     s1 = col[i + 1], s2 = col[i + 2], s3 = col[i + 3];
        int s4 = col[i + 4], s5 = col[i + 5], s6 = col[i + 6], s7 = col[i + 7];
        uint u0 = ((const uint*)(p + (size_t)s0 * F))[lane];
        uint u1 = ((const uint*)(p + (size_t)s1 * F))[lane];
        uint u2 = ((const uint*)(p + (size_t)s2 * F))[lane];
        uint u3 = ((const uint*)(p + (size_t)s3 * F))[lane];
        uint u4 = ((const uint*)(p + (size_t)s4 * F))[lane];
        uint u5 = ((const uint*)(p + (size_t)s5 * F))[lane];
        uint u6 = ((const uint*)(p + (size_t)s6 * F))[lane];
        uint u7 = ((const uint*)(p + (size_t)s7 * F))[lane];
#pragma unroll
        for (int j = 0; j < 8; ++j) {
            uint u = (j == 0) ? u0 : (j == 1) ? u1 : (j == 2) ? u2 : (j == 3) ? u3
                   : (j == 4) ? u4 : (j == 5) ? u5 : (j == 6) ? u6 : u7;
            f32x2 lo = __builtin_amdgcn_cvt_pk_f32_fp8((int)u, false);
            f32x2 hi = __builtin_amdgcn_cvt_pk_f32_fp8((int)u, true);
            a0 += lo.x; a1 += lo.y; a2 += hi.x; a3 += hi.y;
        }
    }
    for (; i < rp1; ++i) {
        int s = col[i];
        uint u = ((const uint*)(p + (size_t)s * F))[lane];
        f32x2 lo = __builtin_amdgcn_cvt_pk_f32_fp8((int)u, false);
        f32x2 hi = __builtin_amdgcn_cvt_pk_f32_fp8((int)u, true);
        a0 += lo.x; a1 += lo.y; a2 += hi.x; a3 += hi.y;
    }
    uchar4 o;
    o.x = f2fp8(a0 * d); o.y = f2fp8(a1 * d); o.z = f2fp8(a2 * d); o.w = f2fp8(a3 * d);
    ((uchar4*)(out + (size_t)v * F))[lane] = o;
}

// ---- merged W repack (fp8) for 32x32x16: all 4 layers in one launch ----
__device__ __forceinline__ void repack_one(const float* W, unsigned char* Wp, int KT, int tid) {
    int lane = tid & 63;
    int kt = (tid >> 6) % KT;
    int nt = (tid >> 6) / KT;
    int n = nt * 32 + (lane & 31);
    int kb = kt * 16 + (lane >> 5) * 8;
    uchar4 lo, hi;
    lo.x = f2fp8(W[(size_t)(kb + 0) * HIDDEN + n]);
    lo.y = f2fp8(W[(size_t)(kb + 1) * HIDDEN + n]);
    lo.z = f2fp8(W[(size_t)(kb + 2) * HIDDEN + n]);
    lo.w = f2fp8(W[(size_t)(kb + 3) * HIDDEN + n]);
    hi.x = f2fp8(W[(size_t)(kb + 4) * HIDDEN + n]);
    hi.y = f2fp8(W[(size_t)(kb + 5) * HIDDEN + n]);
    hi.z = f2fp8(W[(size_t)(kb + 6) * HIDDEN + n]);
    hi.w = f2fp8(W[(size_t)(kb + 7) * HIDDEN + n]);
    ((uchar4*)(Wp + (size_t)tid * 8))[0] = lo;
    ((uchar4*)(Wp + (size_t)tid * 8))[1] = hi;
}

__global__ __launch_bounds__(256) void k_repackAll(const float* __restrict__ W1,
                                                   const float* __restrict__ Wsp,
                                                   unsigned char* __restrict__ Wp1,
                                                   unsigned char* __restrict__ Wp2,
                                                   unsigned char* __restrict__ Wp3,
                                                   unsigned char* __restrict__ Wp4) {
    const int N1 = 8 * 8 * 64;        // 4096 (K=128)
    const int NH = 8 * 16 * 64;       // 8192 (K=256)
    int tid = blockIdx.x * 256 + threadIdx.x;
    if (tid < N1) repack_one(W1, Wp1, 8, tid);
    else if (tid < N1 + NH) repack_one(Wsp + 0 * HIDDEN * HIDDEN, Wp2, 16, tid - N1);
    else if (tid < N1 + 2 * NH) repack_one(Wsp + 1 * HIDDEN * HIDDEN, Wp3, 16, tid - N1 - NH);
    else if (tid < N1 + 3 * NH) repack_one(Wsp + 2 * HIDDEN * HIDDEN, Wp4, 16, tid - N1 - 2 * NH);
}

// ---------------- MFMA GEMM (32x32x16 fp8_fp8, quarter-col): h8 = fp8(epi(A @ W + b)) ----------------
// block = 512 threads = 8 waves: 2 row-groups x 4 col-quarters; wave = 32 rows x 64 cols
// (2 n-tiles, 32 acc VGPR) -> 6256 waves (~24/CU, 6/SIMD) for latency hiding.
// A frag (8 fp8/lane as i64): row = lane&31, k = (lane>>5)*8+j. C/D: col = lane&31,
// row = (reg&3) + 8*(reg>>2) + 4*(lane>>5)  [C/D layout dtype-independent, m121/m127].
// EPI: 0 = BN+relu then *dinv ; 1 = relu then *dinv ; 2 = relu (plain)
template <int KDIM, int EPI>
__global__ __launch_bounds__(512) void k_mgemm(const unsigned char* __restrict__ A,
                                               const unsigned char* __restrict__ Wp,
                                               const float* __restrict__ bias,
                                               const float* __restrict__ gamma,
                                               const float* __restrict__ beta,
                                               const float* __restrict__ mean,
                                               const float* __restrict__ var,
                                               const float* __restrict__ dinv,
                                               unsigned char* __restrict__ out) {
    constexpr int KT = KDIM / 16;
    int t = threadIdx.x;
    int wv = t >> 6, lane = t & 63;
    int rg = wv >> 2;                 // row-group 0..1
    int cq = wv & 3;                  // col-quarter 0..3
    int row0 = blockIdx.x * 64 + rg * 32;
    int nt0 = cq * 2;
    int r32 = lane & 31, hh = lane >> 5;
    int arow = row0 + r32;
    if (arow >= N_NODES) arow = N_NODES - 1;   // safe load; store guarded

    f32x16 acc[2];
#pragma unroll
    for (int j = 0; j < 2; ++j)
#pragma unroll
        for (int r = 0; r < 16; ++r) acc[j][r] = 0.f;

    const unsigned char* aptr = A + (size_t)arow * KDIM + hh * 8;
#pragma unroll
    for (int kt = 0; kt < KT; ++kt) {
        long av = *(const long*)(aptr + kt * 16);
#pragma unroll
        for (int j = 0; j < 2; ++j) {
            long bv = *(const long*)(Wp + ((size_t)((nt0 + j) * KT + kt) * 64 + lane) * 8);
            acc[j] = __builtin_amdgcn_mfma_f32_32x32x16_fp8_fp8(av, bv, acc[j], 0, 0, 0);
        }
    }

    // epilogue
    int rowb = row0 + 4 * hh;
    float bi[2], sc[2], sh[2];
#pragma unroll
    for (int j = 0; j < 2; ++j) {
        int colc = (nt0 + j) * 32 + r32;
        bi[j] = bias[colc];
        if constexpr (EPI == 0) {
            float s = gamma[colc] * rsqrtf(var[colc] + BN_EPS);
            sc[j] = s; sh[j] = beta[colc] - mean[colc] * s;
        }
    }
#pragma unroll
    for (int r = 0; r < 16; ++r) {
        int grow = rowb + (r & 3) + 8 * (r >> 2);
        if (grow < N_NODES) {
            float d = (EPI == 2) ? 1.f : dinv[grow];
#pragma unroll
            for (int j = 0; j < 2; ++j) {
                float y = acc[j][r] + bi[j];
                if constexpr (EPI == 0) y = y * sc[j] + sh[j];
                y = fmaxf(y, 0.f);
                y *= d;
                out[(size_t)grow * HIDDEN + (nt0 + j) * 32 + r32] = f2fp8(y);
            }
        }
    }
}

// ---------------- pooling: chunked segment-sum over fp8 h4, atomics into sums ----------------
__global__ __launch_bounds__(256) void k_pool2(const unsigned char* __restrict__ h,
                                               const int* __restrict__ nlist,
                                               const int* __restrict__ goff,
                                               float* __restrict__ sums) {
    int bid = blockIdx.x;
    int chunk = bid & 3;
    int half = (bid >> 2) & 1;
    int g = bid >> 3;
    int lo = goff[g], hi = goff[g + 1];
    int w = threadIdx.x >> 6, l = threadIdx.x & 63;
    const unsigned char* hp = h + half * 128 + l * 2;
    float a0 = 0.f, a1 = 0.f;
    int i = lo + chunk * 4 + w;          // stride 16 across (chunk, wave)
    for (; i + 48 < hi; i += 64) {
        int v0 = nlist[i], v1 = nlist[i + 16], v2 = nlist[i + 32], v3 = nlist[i + 48];
        uchar2 q0 = *(const uchar2*)(hp + (size_t)v0 * HIDDEN);
        uchar2 q1 = *(const uchar2*)(hp + (size_t)v1 * HIDDEN);
        uchar2 q2 = *(const uchar2*)(hp + (size_t)v2 * HIDDEN);
        uchar2 q3 = *(const uchar2*)(hp + (size_t)v3 * HIDDEN);
        f32x2 d0 = __builtin_amdgcn_cvt_pk_f32_fp8((int)(q0.x | (q0.y << 8)), false);
        f32x2 d1 = __builtin_amdgcn_cvt_pk_f32_fp8((int)(q1.x | (q1.y << 8)), false);
        f32x2 d2 = __builtin_amdgcn_cvt_pk_f32_fp8((int)(q2.x | (q2.y << 8)), false);
        f32x2 d3 = __builtin_amdgcn_cvt_pk_f32_fp8((int)(q3.x | (q3.y << 8)), false);
        a0 += d0.x + d1.x + d2.x + d3.x;
        a1 += d0.y + d1.y + d2.y + d3.y;
    }
    for (; i < hi; i += 16) {
        int v = nlist[i];
        uchar2 q = *(const uchar2*)(hp + (size_t)v * HIDDEN);
        f32x2 dv = __builtin_amdgcn_cvt_pk_f32_fp8((int)(q.x | (q.y << 8)), false);
        a0 += dv.x; a1 += dv.y;
    }
    __shared__ float red[4][128];
    red[w][l * 2] = a0;
    red[w][l * 2 + 1] = a1;
    __syncthreads();
    int t = threadIdx.x;
    if (t < 128) {
        float s = red[0][t] + red[1][t] + red[2][t] + red[3][t];
        atomicAdd(&sums[(size_t)g * HIDDEN + half * 128 + t], s);
    }
}

// ---------------- logits + log_softmax per graph ----------------
__global__ __launch_bounds__(256) void k_logits(const float* __restrict__ sums,
                                                const int* __restrict__ gcnt,
                                                const float* __restrict__ W2,
                                                const float* __restrict__ b2,
                                                float* __restrict__ outp) {
    __shared__ float pooled[HIDDEN];
    int g = blockIdx.x;
    int t = threadIdx.x;
    float inv = 1.0f / fmaxf((float)gcnt[g], 1.0f);
    pooled[t] = sums[(size_t)g * HIDDEN + t] * inv;
    __syncthreads();
    if (t < 64) {
        float lg = -INFINITY;
        if (t < NUM_CLASSES) {
            lg = b2[t];
            for (int k = 0; k < HIDDEN; ++k) lg += pooled[k] * W2[k * NUM_CLASSES + t];
        }
        float m = lg;
        for (int off = 1; off < 16; off <<= 1) m = fmaxf(m, __shfl_xor(m, off));
        float e = (t < 16) ? expf(lg - m) : 0.f;
        float ssum = e;
        for (int off = 1; off < 16; off <<= 1) ssum += __shfl_xor(ssum, off);
        if (t < NUM_CLASSES) outp[g * NUM_CLASSES + t] = lg - m - logf(ssum);
    }
}

extern "C" void kernel_launch(void* const* d_in, const int* in_sizes, int n_in,
                              void* d_out, int out_size, void* d_ws, size_t ws_size,
                              hipStream_t stream) {
    const float* x     = (const float*)d_in[0];
    const int*   ei    = (const int*)d_in[1];
    const int*   batch = (const int*)d_in[2];
    const float* W1    = (const float*)d_in[3];
    const float* b1    = (const float*)d_in[4];
    const float* gamma = (const float*)d_in[5];
    const float* beta  = (const float*)d_in[6];
    const float* rmean = (const float*)d_in[7];
    const float* rvar  = (const float*)d_in[8];
    const float* Wsp   = (const float*)d_in[9];
    const float* bsp   = (const float*)d_in[10];
    const float* W2    = (const float*)d_in[11];
    const float* b2    = (const float*)d_in[12];
    float* out = (float*)d_out;

    char* w = (char*)d_ws;
    size_t off = 0;
    auto alloc = [&](size_t bytes) -> void* {
        void* p = w + off;
        off = (off + bytes + 255) & ~(size_t)255;
        return p;
    };
    int*    cnt    = (int*)alloc((size_t)N_NODES * 4);
    int*    gcnt   = (int*)alloc((size_t)NUM_GRAPHS * 4);
    int*    rowp   = (int*)alloc((size_t)(N_NODES + 1) * 4);
    int*    bincur = (int*)alloc((size_t)NBINS * 4);
    uint*   pairs  = (uint*)alloc((size_t)N_EDGES * 4);
    int*    col    = (int*)alloc((size_t)N_EDGES * 4);
    float*  dinv   = (float*)alloc((size_t)N_NODES * 4);
    int*    csum   = (int*)alloc((size_t)NCHUNK * 4);
    int*    choff  = (int*)alloc((size_t)NCHUNK * 4);
    int*    goff   = (int*)alloc((size_t)(NUM_GRAPHS + 1) * 4);
    int*    gcur   = (int*)alloc((size_t)NUM_GRAPHS * 4);
    int*    nlist  = (int*)alloc((size_t)N_NODES * 4);
    float*  sums   = (float*)alloc((size_t)NUM_GRAPHS * HIDDEN * 4);
    unsigned char* Wp1 = (unsigned char*)alloc((size_t)8 * 8 * 64 * 8);
    unsigned char* Wp2 = (unsigned char*)alloc((size_t)8 * 16 * 64 * 8);
    unsigned char* Wp3 = (unsigned char*)alloc((size_t)8 * 16 * 64 * 8);
    unsigned char* Wp4 = (unsigned char*)alloc((size_t)8 * 16 * 64 * 8);
    unsigned char* a8  = (unsigned char*)alloc((size_t)N_NODES * HIDDEN);
    unsigned char* p8  = (unsigned char*)alloc((size_t)N_NODES * IN_FEAT);
    unsigned char* h8  = (unsigned char*)alloc((size_t)N_NODES * HIDDEN);

    hipMemsetAsync(cnt, 0, (size_t)N_NODES * 4, stream);
    hipMemsetAsync(gcnt, 0, (size_t)NUM_GRAPHS * 4, stream);
    hipMemsetAsync(sums, 0, (size_t)NUM_GRAPHS * HIDDEN * 4, stream);

    const int* srcp = ei;
    const int* dstp = ei + N_EDGES;

    // CSR + degree + graph buckets
    k_count<<<(N_EDGES + 255) / 256, 256, 0, stream>>>(dstp, cnt);
    k_count_batch<<<(N_NODES + 511) / 512, 512, 0, stream>>>(batch, gcnt);
    k_chunksum<<<NCHUNK, 256, 0, stream>>>(cnt, csum);
    k_scan2<<<2, 256, 0, stream>>>(csum, choff, gcnt, goff, gcur);
    k_apply<<<NCHUNK, 256, 0, stream>>>(cnt, choff, rowp, dinv, bincur);
    k_binA<<<(N_EDGES + 256 * FILLA_EPT - 1) / (256 * FILLA_EPT), 256, 0, stream>>>(
        srcp, dstp, bincur, pairs);
    k_binB<<<NBINS, 512, 0, stream>>>(pairs, rowp, col);
    k_fillg<<<(N_NODES + 511) / 512, 512, 0, stream>>>(batch, gcur, nlist);

    // weight repack (fp8, all 4 layers, one launch)
    k_repackAll<<<(8 * 8 * 64 + 3 * 8 * 16 * 64 + 255) / 256, 256, 0, stream>>>(
        W1, Wsp, Wp1, Wp2, Wp3, Wp4);

    const int GG = (N_NODES + 63) / 64;
    const int NB4 = (N_NODES + 3) / 4;

    // layer 1 (fp8 gather of x*dinv; fp8 A; fp8 output h1)
    k_prescale<<<(N_NODES * IN_FEAT / 4 + 255) / 256, 256, 0, stream>>>(x, dinv, p8);
    k_agg128<<<NB4, 256, 0, stream>>>(p8, col, rowp, dinv, a8);
    k_mgemm<IN_FEAT, 0><<<GG, 512, 0, stream>>>(a8, Wp1, b1, gamma, beta, rmean, rvar, dinv, h8);

    // layers 2..3 (fp8 gather; fp8 output)
    k_agg8<<<NB4, 256, 0, stream>>>(h8, col, rowp, dinv, a8);
    k_mgemm<HIDDEN, 1><<<GG, 512, 0, stream>>>(a8, Wp2, bsp + 0 * HIDDEN,
                                               nullptr, nullptr, nullptr, nullptr, dinv, h8);

    k_agg8<<<NB4, 256, 0, stream>>>(h8, col, rowp, dinv, a8);
    k_mgemm<HIDDEN, 1><<<GG, 512, 0, stream>>>(a8, Wp3, bsp + 1 * HIDDEN,
                                               nullptr, nullptr, nullptr, nullptr, dinv, h8);

    // layer 4 (plain relu; fp8 h4 feeds pooling)
    k_agg8<<<NB4, 256, 0, stream>>>(h8, col, rowp, dinv, a8);
    k_mgemm<HIDDEN, 2><<<GG, 512, 0, stream>>>(a8, Wp4, bsp + 2 * HIDDEN,
                                               nullptr, nullptr, nullptr, nullptr, dinv, h8);

    k_pool2<<<NUM_GRAPHS * 2 * 4, 256, 0, stream>>>(h8, nlist, goff, sums);
    k_logits<<<NUM_GRAPHS, 256, 0, stream>>>(sums, gcnt, W2, b2, out);
}

// Round 20
// 357.159 us; speedup vs baseline: 1.0583x; 1.0583x over previous
//
#include <hip/hip_runtime.h>
#include <math.h>

#define N_NODES 50000
#define N_EDGES 800000
#define IN_FEAT 128
#define HIDDEN 256
#define NUM_GRAPHS 128
#define NUM_CLASSES 10
#define BN_EPS 1e-5f

#define NCHUNK ((N_NODES + 255) / 256)   // 196 scan chunks
#define BINW 512
#define NBINS ((N_NODES + BINW - 1) / BINW)   // 98

typedef __attribute__((ext_vector_type(16))) float f32x16;
typedef __attribute__((ext_vector_type(2))) float f32x2;

__device__ __forceinline__ ushort f2bf(float f) {
    union { float f; uint u; } c; c.f = f;
    uint u = c.u;
    return (ushort)((u + 0x7FFFu + ((u >> 16) & 1u)) >> 16);   // RNE
}
__device__ __forceinline__ float bf2f(ushort h) {
    union { uint u; float f; } c; c.u = ((uint)h) << 16;
    return c.f;
}
// fp8 e4m3 (hardware cvt, OCP on gfx950); matched encode/decode round-trip
__device__ __forceinline__ unsigned char f2fp8(float f) {
    return (unsigned char)(__builtin_amdgcn_cvt_pk_fp8_f32(f, f, 0, false) & 0xFF);
}

// ---------------- CSR build ----------------
__global__ void k_count(const int* __restrict__ dst, int* __restrict__ cnt) {
    int e = blockIdx.x * 256 + threadIdx.x;
    if (e < N_EDGES) atomicAdd(&cnt[dst[e]], 1);
}

// ---- batch histogram: LDS hist, one global atomic per (block, graph) ----
__global__ __launch_bounds__(512) void k_count_batch(const int* __restrict__ batch,
                                                     int* __restrict__ gcnt) {
    __shared__ int hist[NUM_GRAPHS];
    int t = threadIdx.x;
    if (t < NUM_GRAPHS) hist[t] = 0;
    __syncthreads();
    int v = blockIdx.x * 512 + t;
    if (v < N_NODES) atomicAdd(&hist[batch[v]], 1);
    __syncthreads();
    if (t < NUM_GRAPHS && hist[t] > 0) atomicAdd(&gcnt[t], hist[t]);
}

__global__ __launch_bounds__(256) void k_chunksum(const int* __restrict__ cnt,
                                                  int* __restrict__ csum) {
    int i = blockIdx.x * 256 + threadIdx.x;
    int v = (i < N_NODES) ? cnt[i] : 0;
#pragma unroll
    for (int off = 32; off; off >>= 1) v += __shfl_down(v, off, 64);
    __shared__ int ws[4];
    if ((threadIdx.x & 63) == 0) ws[threadIdx.x >> 6] = v;
    __syncthreads();
    if (threadIdx.x == 0) csum[blockIdx.x] = ws[0] + ws[1] + ws[2] + ws[3];
}

// merged scans: block 0 = chunk-offsets scan; block 1 = graph-offsets scan
__global__ __launch_bounds__(256) void k_scan2(const int* __restrict__ csum,
                                               int* __restrict__ choff,
                                               const int* __restrict__ gcnt,
                                               int* __restrict__ goff,
                                               int* __restrict__ gcur) {
    __shared__ int s[256];
    int t = threadIdx.x;
    if (blockIdx.x == 0) {
        int v = (t < NCHUNK) ? csum[t] : 0;
        s[t] = v;
        __syncthreads();
#pragma unroll
        for (int off = 1; off < 256; off <<= 1) {
            int add = (t >= off) ? s[t - off] : 0;
            __syncthreads();
            s[t] += add;
            __syncthreads();
        }
        if (t < NCHUNK) choff[t] = s[t] - v;   // exclusive
    } else {
        int v = (t < NUM_GRAPHS) ? gcnt[t] : 0;
        s[t] = v;
        __syncthreads();
#pragma unroll
        for (int off = 1; off < NUM_GRAPHS; off <<= 1) {
            int add = (t >= off && t < NUM_GRAPHS) ? s[t - off] : 0;
            __syncthreads();
            if (t < NUM_GRAPHS) s[t] += add;
            __syncthreads();
        }
        if (t < NUM_GRAPHS) {
            goff[t] = s[t] - v;
            gcur[t] = s[t] - v;
            if (t == NUM_GRAPHS - 1) goff[NUM_GRAPHS] = s[t];
        }
    }
}

// k_apply also initializes bincur (folded k_initbins)
__global__ __launch_bounds__(256) void k_apply(const int* __restrict__ cnt,
                                               const int* __restrict__ choff,
                                               int* __restrict__ rowp,
                                               float* __restrict__ dinv,
                                               int* __restrict__ bincur) {
    __shared__ int s[256];
    int t = threadIdx.x;
    int i = blockIdx.x * 256 + t;
    int c = (i < N_NODES) ? cnt[i] : 0;
    s[t] = c;
    __syncthreads();
#pragma unroll
    for (int off = 1; off < 256; off <<= 1) {
        int add = (t >= off) ? s[t - off] : 0;
        __syncthreads();
        s[t] += add;
        __syncthreads();
    }
    int incl = s[t];
    int base = choff[blockIdx.x];
    if (i < N_NODES) {
        int ex = base + incl - c;
        rowp[i] = ex;
        dinv[i] = rsqrtf(1.0f + (float)c);
        if ((i & (BINW - 1)) == 0) bincur[i / BINW] = ex;
        if (i == N_NODES - 1) rowp[N_NODES] = base + incl;
    }
}

#define FILLA_EPT 8   // edges per thread; 392 blocks x 2048 edges
__global__ __launch_bounds__(256) void k_binA(const int* __restrict__ src,
                                              const int* __restrict__ dst,
                                              int* __restrict__ bincur,
                                              uint* __restrict__ pairs) {
    __shared__ int hist[NBINS];
    __shared__ int base[NBINS];
    int t = threadIdx.x;
    for (int i = t; i < NBINS; i += 256) hist[i] = 0;
    __syncthreads();
    int e0 = blockIdx.x * (256 * FILLA_EPT);
    int mybin[FILLA_EPT], myoff[FILLA_EPT];
    uint mypair[FILLA_EPT];
#pragma unroll
    for (int j = 0; j < FILLA_EPT; ++j) {
        int e = e0 + j * 256 + t;
        mybin[j] = -1;
        if (e < N_EDGES) {
            int d = dst[e], s = src[e];
            int b = d >> 9;                       // BINW = 512
            mybin[j] = b;
            mypair[j] = (uint)s | ((uint)(d & (BINW - 1)) << 16);
            myoff[j] = atomicAdd(&hist[b], 1);
        }
    }
    __syncthreads();
    for (int i = t; i < NBINS; i += 256)
        base[i] = atomicAdd(&bincur[i], hist[i]);
    __syncthreads();
#pragma unroll
    for (int j = 0; j < FILLA_EPT; ++j) {
        if (mybin[j] >= 0) pairs[base[mybin[j]] + myoff[j]] = mypair[j];
    }
}

// ---- pass B: one block per bin; LDS cursors; writes confined to bin's col region ----
__global__ __launch_bounds__(512) void k_binB(const uint* __restrict__ pairs,
                                              const int* __restrict__ rowp,
                                              int* __restrict__ col) {
    __shared__ int cur[BINW];
    int b = blockIdx.x;
    int v0 = b * BINW;
    int t = threadIdx.x;
    int vend = min(v0 + BINW, N_NODES);
    for (int i = t; i < vend - v0; i += 512) cur[i] = rowp[v0 + i];
    __syncthreads();
    int lo = rowp[v0];
    int hi = rowp[vend];
    for (int i = lo + t; i < hi; i += 512) {
        uint pr = pairs[i];
        int dl = pr >> 16;
        int s = pr & 0xFFFF;
        int slot = atomicAdd(&cur[dl], 1);
        col[slot] = s;
    }
}

// ---- graph bucketing: LDS histogram, one global atomic per (block, graph) ----
__global__ __launch_bounds__(512) void k_fillg(const int* __restrict__ batch,
                                               int* __restrict__ gcur,
                                               int* __restrict__ nlist) {
    __shared__ int hist[NUM_GRAPHS];
    __shared__ int base[NUM_GRAPHS];
    int t = threadIdx.x;
    if (t < NUM_GRAPHS) hist[t] = 0;
    __syncthreads();
    int v = blockIdx.x * 512 + t;
    int g = -1, off = 0;
    if (v < N_NODES) {
        g = batch[v];
        off = atomicAdd(&hist[g], 1);
    }
    __syncthreads();
    if (t < NUM_GRAPHS) base[t] = atomicAdd(&gcur[t], hist[t]);
    __syncthreads();
    if (g >= 0) nlist[base[g] + off] = v;
}

// ---------------- prescale: p0 = fp8(x * dinv[row]) ----------------
__global__ void k_prescale(const float* __restrict__ x, const float* __restrict__ dinv,
                           unsigned char* __restrict__ p0) {
    int i = blockIdx.x * 256 + threadIdx.x;      // per 4 elems
    if (i < N_NODES * IN_FEAT / 4) {
        float4 v = ((const float4*)x)[i];
        float d = dinv[i / (IN_FEAT / 4)];
        uchar4 o;
        o.x = f2fp8(v.x * d); o.y = f2fp8(v.y * d);
        o.z = f2fp8(v.z * d); o.w = f2fp8(v.w * d);
        ((uchar4*)p0)[i] = o;
    }
}

// ---------------- layer-1 aggregation (fp8 in, fp8 out, 8-deep pipeline) ----------------
__global__ __launch_bounds__(256) void k_agg128(const unsigned char* __restrict__ p,
                                                const int* __restrict__ col,
                                                const int* __restrict__ row_ptr,
                                                const float* __restrict__ dinv,
                                                unsigned char* __restrict__ out) {
    const int F = IN_FEAT;
    int wave = threadIdx.x >> 6;
    int lane = threadIdx.x & 63;
    int v = blockIdx.x * 4 + wave;
    if (v >= N_NODES) return;
    int rp0 = row_ptr[v], rp1 = row_ptr[v + 1];
    float d = dinv[v];
    ushort um = ((const ushort*)(p + (size_t)v * F))[lane];
    f32x2 m = __builtin_amdgcn_cvt_pk_f32_fp8((int)um, false);
    float a0 = m.x, a1 = m.y;
    int i = rp0;
    for (; i + 8 <= rp1; i += 8) {
        int s0 = col[i],     s1 = col[i + 1], s2 = col[i + 2], s3 = col[i + 3];
        int s4 = col[i + 4], s5 = col[i + 5], s6 = col[i + 6], s7 = col[i + 7];
        ushort u0 = ((const ushort*)(p + (size_t)s0 * F))[lane];
        ushort u1 = ((const ushort*)(p + (size_t)s1 * F))[lane];
        ushort u2 = ((const ushort*)(p + (size_t)s2 * F))[lane];
        ushort u3 = ((const ushort*)(p + (size_t)s3 * F))[lane];
        ushort u4 = ((const ushort*)(p + (size_t)s4 * F))[lane];
        ushort u5 = ((const ushort*)(p + (size_t)s5 * F))[lane];
        ushort u6 = ((const ushort*)(p + (size_t)s6 * F))[lane];
        ushort u7 = ((const ushort*)(p + (size_t)s7 * F))[lane];
        f32x2 d0 = __builtin_amdgcn_cvt_pk_f32_fp8((int)u0, false);
        f32x2 d1 = __builtin_amdgcn_cvt_pk_f32_fp8((int)u1, false);
        f32x2 d2 = __builtin_amdgcn_cvt_pk_f32_fp8((int)u2, false);
        f32x2 d3 = __builtin_amdgcn_cvt_pk_f32_fp8((int)u3, false);
        f32x2 d4 = __builtin_amdgcn_cvt_pk_f32_fp8((int)u4, false);
        f32x2 d5 = __builtin_amdgcn_cvt_pk_f32_fp8((int)u5, false);
        f32x2 d6 = __builtin_amdgcn_cvt_pk_f32_fp8((int)u6, false);
        f32x2 d7 = __builtin_amdgcn_cvt_pk_f32_fp8((int)u7, false);
        a0 += d0.x + d1.x + d2.x + d3.x + d4.x + d5.x + d6.x + d7.x;
        a1 += d0.y + d1.y + d2.y + d3.y + d4.y + d5.y + d6.y + d7.y;
    }
    for (; i < rp1; ++i) {
        int s = col[i];
        ushort u = ((const ushort*)(p + (size_t)s * F))[lane];
        f32x2 dv = __builtin_amdgcn_cvt_pk_f32_fp8((int)u, false);
        a0 += dv.x; a1 += dv.y;
    }
    uchar2 o;
    o.x = f2fp8(a0 * d); o.y = f2fp8(a1 * d);
    ((uchar2*)(out + (size_t)v * F))[lane] = o;
}

// ---------------- hidden-layer aggregation (fp8 in, fp8 out, 8-deep pipeline) ----------------
__global__ __launch_bounds__(256) void k_agg8(const unsigned char* __restrict__ p,
                                              const int* __restrict__ col,
                                              const int* __restrict__ row_ptr,
                                              const float* __restrict__ dinv,
                                              unsigned char* __restrict__ out) {
    const int F = HIDDEN;
    int wave = threadIdx.x >> 6;
    int lane = threadIdx.x & 63;
    int v = blockIdx.x * 4 + wave;
    if (v >= N_NODES) return;
    int rp0 = row_ptr[v], rp1 = row_ptr[v + 1];
    float d = dinv[v];
    uint um = ((const uint*)(p + (size_t)v * F))[lane];
    f32x2 mlo = __builtin_amdgcn_cvt_pk_f32_fp8((int)um, false);
    f32x2 mhi = __builtin_amdgcn_cvt_pk_f32_fp8((int)um, true);
    float a0 = mlo.x, a1 = mlo.y, a2 = mhi.x, a3 = mhi.y;
    int i = rp0;
    for (; i + 8 <= rp1; i += 8) {
        int s0 = col[i],     s1 = col[i + 1], s2 = col[i + 2], s3 = col[i + 3];
        int s4 = col[i + 4], s5 = col[i + 5], s6 = col[i + 6], s7 = col[i + 7];
        uint u0 = ((const uint*)(p + (size_t)s0 * F))[lane];
        uint u1 = ((const uint*)(p + (size_t)s1 * F))[lane];
        uint u2 = ((const uint*)(p + (size_t)s2 * F))[lane];
        uint u3 = ((const uint*)(p + (size_t)s3 * F))[lane];
        uint u4 = ((const uint*)(p + (size_t)s4 * F))[lane];
        uint u5 = ((const uint*)(p + (size_t)s5 * F))[lane];
        uint u6 = ((const uint*)(p + (size_t)s6 * F))[lane];
        uint u7 = ((const uint*)(p + (size_t)s7 * F))[lane];
#pragma unroll
        for (int j = 0; j < 8; ++j) {
            uint u = (j == 0) ? u0 : (j == 1) ? u1 : (j == 2) ? u2 : (j == 3) ? u3
                   : (j == 4) ? u4 : (j == 5) ? u5 : (j == 6) ? u6 : u7;
            f32x2 lo = __builtin_amdgcn_cvt_pk_f32_fp8((int)u, false);
            f32x2 hi = __builtin_amdgcn_cvt_pk_f32_fp8((int)u, true);
            a0 += lo.x; a1 += lo.y; a2 += hi.x; a3 += hi.y;
        }
    }
    for (; i < rp1; ++i) {
        int s = col[i];
        uint u = ((const uint*)(p + (size_t)s * F))[lane];
        f32x2 lo = __builtin_amdgcn_cvt_pk_f32_fp8((int)u, false);
        f32x2 hi = __builtin_amdgcn_cvt_pk_f32_fp8((int)u, true);
        a0 += lo.x; a1 += lo.y; a2 += hi.x; a3 += hi.y;
    }
    uchar4 o;
    o.x = f2fp8(a0 * d); o.y = f2fp8(a1 * d); o.z = f2fp8(a2 * d); o.w = f2fp8(a3 * d);
    ((uchar4*)(out + (size_t)v * F))[lane] = o;
}

// ---- merged W repack (fp8) for 32x32x16: all 4 layers in one launch ----
__device__ __forceinline__ void repack_one(const float* W, unsigned char* Wp, int KT, int tid) {
    int lane = tid & 63;
    int kt = (tid >> 6) % KT;
    int nt = (tid >> 6) / KT;
    int n = nt * 32 + (lane & 31);
    int kb = kt * 16 + (lane >> 5) * 8;
    uchar4 lo, hi;
    lo.x = f2fp8(W[(size_t)(kb + 0) * HIDDEN + n]);
    lo.y = f2fp8(W[(size_t)(kb + 1) * HIDDEN + n]);
    lo.z = f2fp8(W[(size_t)(kb + 2) * HIDDEN + n]);
    lo.w = f2fp8(W[(size_t)(kb + 3) * HIDDEN + n]);
    hi.x = f2fp8(W[(size_t)(kb + 4) * HIDDEN + n]);
    hi.y = f2fp8(W[(size_t)(kb + 5) * HIDDEN + n]);
    hi.z = f2fp8(W[(size_t)(kb + 6) * HIDDEN + n]);
    hi.w = f2fp8(W[(size_t)(kb + 7) * HIDDEN + n]);
    ((uchar4*)(Wp + (size_t)tid * 8))[0] = lo;
    ((uchar4*)(Wp + (size_t)tid * 8))[1] = hi;
}

__global__ __launch_bounds__(256) void k_repackAll(const float* __restrict__ W1,
                                                   const float* __restrict__ Wsp,
                                                   unsigned char* __restrict__ Wp1,
                                                   unsigned char* __restrict__ Wp2,
                                                   unsigned char* __restrict__ Wp3,
                                                   unsigned char* __restrict__ Wp4) {
    const int N1 = 8 * 8 * 64;        // 4096 (K=128)
    const int NH = 8 * 16 * 64;       // 8192 (K=256)
    int tid = blockIdx.x * 256 + threadIdx.x;
    if (tid < N1) repack_one(W1, Wp1, 8, tid);
    else if (tid < N1 + NH) repack_one(Wsp + 0 * HIDDEN * HIDDEN, Wp2, 16, tid - N1);
    else if (tid < N1 + 2 * NH) repack_one(Wsp + 1 * HIDDEN * HIDDEN, Wp3, 16, tid - N1 - NH);
    else if (tid < N1 + 3 * NH) repack_one(Wsp + 2 * HIDDEN * HIDDEN, Wp4, 16, tid - N1 - 2 * NH);
}

// ---------------- MFMA GEMM (32x32x16 fp8_fp8, LDS-staged B): h8 = fp8(epi(A@W+b)) ----------------
// block = 256 threads = 4 waves (2 row-groups x 2 col-halves); wave = 32 rows x 128 cols.
// B (whole repacked W, 8*KT*512 bytes = 32/64 KB fp8) is cooperatively staged into LDS
// once; each lane prefetches all KT A-fragments into registers; the K-loop is then pure
// ds_read + MFMA (R19 showed the global-load dependent chain was the stall).
// A frag (8 fp8/lane as i64): row = lane&31, k = (lane>>5)*8+j. C/D: col = lane&31,
// row = (reg&3) + 8*(reg>>2) + 4*(lane>>5)  [C/D layout dtype-independent, m121/m127].
// EPI: 0 = BN+relu then *dinv ; 1 = relu then *dinv ; 2 = relu (plain)
template <int KDIM, int EPI>
__global__ __launch_bounds__(256) void k_mgemm(const unsigned char* __restrict__ A,
                                               const unsigned char* __restrict__ Wp,
                                               const float* __restrict__ bias,
                                               const float* __restrict__ gamma,
                                               const float* __restrict__ beta,
                                               const float* __restrict__ mean,
                                               const float* __restrict__ var,
                                               const float* __restrict__ dinv,
                                               unsigned char* __restrict__ out) {
    constexpr int KT = KDIM / 16;
    constexpr int BTOT = 8 * KT * 64 * 8;    // 32768 (K=128) / 65536 (K=256) bytes
    __shared__ unsigned char Bs[BTOT];
    int t = threadIdx.x;
    // cooperative stage: 16B per thread per step, fully coalesced
#pragma unroll
    for (int i = t * 16; i < BTOT; i += 256 * 16)
        *(float4*)(Bs + i) = *(const float4*)(Wp + i);

    int wv = t >> 6, lane = t & 63;
    int rg = wv >> 1;                 // row-group 0..1
    int ch = wv & 1;                  // col-half 0..1
    int row0 = blockIdx.x * 64 + rg * 32;
    int nt0 = ch * 4;
    int r32 = lane & 31, hh = lane >> 5;
    int arow = row0 + r32;
    if (arow >= N_NODES) arow = N_NODES - 1;   // safe load; store guarded

    // prefetch all A fragments (KT x 8B per lane) into registers
    long av[KT];
    const unsigned char* aptr = A + (size_t)arow * KDIM + hh * 8;
#pragma unroll
    for (int kt = 0; kt < KT; ++kt) av[kt] = *(const long*)(aptr + kt * 16);

    f32x16 acc[4];
#pragma unroll
    for (int j = 0; j < 4; ++j)
#pragma unroll
        for (int r = 0; r < 16; ++r) acc[j][r] = 0.f;

    __syncthreads();   // Bs ready (A prefetch in flight / waited by compiler at first use)

#pragma unroll
    for (int kt = 0; kt < KT; ++kt) {
#pragma unroll
        for (int j = 0; j < 4; ++j) {
            long bv = *(const long*)(Bs + ((size_t)((nt0 + j) * KT + kt) * 64 + lane) * 8);
            acc[j] = __builtin_amdgcn_mfma_f32_32x32x16_fp8_fp8(av[kt], bv, acc[j], 0, 0, 0);
        }
    }

    // epilogue
    int rowb = row0 + 4 * hh;
    float bi[4], sc[4], sh[4];
#pragma unroll
    for (int j = 0; j < 4; ++j) {
        int colc = (nt0 + j) * 32 + r32;
        bi[j] = bias[colc];
        if constexpr (EPI == 0) {
            float s = gamma[colc] * rsqrtf(var[colc] + BN_EPS);
            sc[j] = s; sh[j] = beta[colc] - mean[colc] * s;
        }
    }
#pragma unroll
    for (int r = 0; r < 16; ++r) {
        int grow = rowb + (r & 3) + 8 * (r >> 2);
        if (grow < N_NODES) {
            float d = (EPI == 2) ? 1.f : dinv[grow];
#pragma unroll
            for (int j = 0; j < 4; ++j) {
                float y = acc[j][r] + bi[j];
                if constexpr (EPI == 0) y = y * sc[j] + sh[j];
                y = fmaxf(y, 0.f);
                y *= d;
                out[(size_t)grow * HIDDEN + (nt0 + j) * 32 + r32] = f2fp8(y);
            }
        }
    }
}

// ---------------- pooling: chunked segment-sum over fp8 h4, atomics into sums ----------------
__global__ __launch_bounds__(256) void k_pool2(const unsigned char* __restrict__ h,
                                               const int* __restrict__ nlist,
                                               const int* __restrict__ goff,
                                               float* __restrict__ sums) {
    int bid = blockIdx.x;
    int chunk = bid & 3;
    int half = (bid >> 2) & 1;
    int g = bid >> 3;
    int lo = goff[g], hi = goff[g + 1];
    int w = threadIdx.x >> 6, l = threadIdx.x & 63;
    const unsigned char* hp = h + half * 128 + l * 2;
    float a0 = 0.f, a1 = 0.f;
    int i = lo + chunk * 4 + w;          // stride 16 across (chunk, wave)
    for (; i + 48 < hi; i += 64) {
        int v0 = nlist[i], v1 = nlist[i + 16], v2 = nlist[i + 32], v3 = nlist[i + 48];
        uchar2 q0 = *(const uchar2*)(hp + (size_t)v0 * HIDDEN);
        uchar2 q1 = *(const uchar2*)(hp + (size_t)v1 * HIDDEN);
        uchar2 q2 = *(const uchar2*)(hp + (size_t)v2 * HIDDEN);
        uchar2 q3 = *(const uchar2*)(hp + (size_t)v3 * HIDDEN);
        f32x2 d0 = __builtin_amdgcn_cvt_pk_f32_fp8((int)(q0.x | (q0.y << 8)), false);
        f32x2 d1 = __builtin_amdgcn_cvt_pk_f32_fp8((int)(q1.x | (q1.y << 8)), false);
        f32x2 d2 = __builtin_amdgcn_cvt_pk_f32_fp8((int)(q2.x | (q2.y << 8)), false);
        f32x2 d3 = __builtin_amdgcn_cvt_pk_f32_fp8((int)(q3.x | (q3.y << 8)), false);
        a0 += d0.x + d1.x + d2.x + d3.x;
        a1 += d0.y + d1.y + d2.y + d3.y;
    }
    for (; i < hi; i += 16) {
        int v = nlist[i];
        uchar2 q = *(const uchar2*)(hp + (size_t)v * HIDDEN);
        f32x2 dv = __builtin_amdgcn_cvt_pk_f32_fp8((int)(q.x | (q.y << 8)), false);
        a0 += dv.x; a1 += dv.y;
    }
    __shared__ float red[4][128];
    red[w][l * 2] = a0;
    red[w][l * 2 + 1] = a1;
    __syncthreads();
    int t = threadIdx.x;
    if (t < 128) {
        float s = red[0][t] + red[1][t] + red[2][t] + red[3][t];
        atomicAdd(&sums[(size_t)g * HIDDEN + half * 128 + t], s);
    }
}

// ---------------- logits + log_softmax per graph ----------------
__global__ __launch_bounds__(256) void k_logits(const float* __restrict__ sums,
                                                const int* __restrict__ gcnt,
                                                const float* __restrict__ W2,
                                                const float* __restrict__ b2,
                                                float* __restrict__ outp) {
    __shared__ float pooled[HIDDEN];
    int g = blockIdx.x;
    int t = threadIdx.x;
    float inv = 1.0f / fmaxf((float)gcnt[g], 1.0f);
    pooled[t] = sums[(size_t)g * HIDDEN + t] * inv;
    __syncthreads();
    if (t < 64) {
        float lg = -INFINITY;
        if (t < NUM_CLASSES) {
            lg = b2[t];
            for (int k = 0; k < HIDDEN; ++k) lg += pooled[k] * W2[k * NUM_CLASSES + t];
        }
        float m = lg;
        for (int off = 1; off < 16; off <<= 1) m = fmaxf(m, __shfl_xor(m, off));
        float e = (t < 16) ? expf(lg - m) : 0.f;
        float ssum = e;
        for (int off = 1; off < 16; off <<= 1) ssum += __shfl_xor(ssum, off);
        if (t < NUM_CLASSES) outp[g * NUM_CLASSES + t] = lg - m - logf(ssum);
    }
}

extern "C" void kernel_launch(void* const* d_in, const int* in_sizes, int n_in,
                              void* d_out, int out_size, void* d_ws, size_t ws_size,
                              hipStream_t stream) {
    const float* x     = (const float*)d_in[0];
    const int*   ei    = (const int*)d_in[1];
    const int*   batch = (const int*)d_in[2];
    const float* W1    = (const float*)d_in[3];
    const float* b1    = (const float*)d_in[4];
    const float* gamma = (const float*)d_in[5];
    const float* beta  = (const float*)d_in[6];
    const float* rmean = (const float*)d_in[7];
    const float* rvar  = (const float*)d_in[8];
    const float* Wsp   = (const float*)d_in[9];
    const float* bsp   = (const float*)d_in[10];
    const float* W2    = (const float*)d_in[11];
    const float* b2    = (const float*)d_in[12];
    float* out = (float*)d_out;

    char* w = (char*)d_ws;
    size_t off = 0;
    auto alloc = [&](size_t bytes) -> void* {
        void* p = w + off;
        off = (off + bytes + 255) & ~(size_t)255;
        return p;
    };
    int*    cnt    = (int*)alloc((size_t)N_NODES * 4);
    int*    gcnt   = (int*)alloc((size_t)NUM_GRAPHS * 4);
    int*    rowp   = (int*)alloc((size_t)(N_NODES + 1) * 4);
    int*    bincur = (int*)alloc((size_t)NBINS * 4);
    uint*   pairs  = (uint*)alloc((size_t)N_EDGES * 4);
    int*    col    = (int*)alloc((size_t)N_EDGES * 4);
    float*  dinv   = (float*)alloc((size_t)N_NODES * 4);
    int*    csum   = (int*)alloc((size_t)NCHUNK * 4);
    int*    choff  = (int*)alloc((size_t)NCHUNK * 4);
    int*    goff   = (int*)alloc((size_t)(NUM_GRAPHS + 1) * 4);
    int*    gcur   = (int*)alloc((size_t)NUM_GRAPHS * 4);
    int*    nlist  = (int*)alloc((size_t)N_NODES * 4);
    float*  sums   = (float*)alloc((size_t)NUM_GRAPHS * HIDDEN * 4);
    unsigned char* Wp1 = (unsigned char*)alloc((size_t)8 * 8 * 64 * 8);
    unsigned char* Wp2 = (unsigned char*)alloc((size_t)8 * 16 * 64 * 8);
    unsigned char* Wp3 = (unsigned char*)alloc((size_t)8 * 16 * 64 * 8);
    unsigned char* Wp4 = (unsigned char*)alloc((size_t)8 * 16 * 64 * 8);
    unsigned char* a8  = (unsigned char*)alloc((size_t)N_NODES * HIDDEN);
    unsigned char* p8  = (unsigned char*)alloc((size_t)N_NODES * IN_FEAT);
    unsigned char* h8  = (unsigned char*)alloc((size_t)N_NODES * HIDDEN);

    hipMemsetAsync(cnt, 0, (size_t)N_NODES * 4, stream);
    hipMemsetAsync(gcnt, 0, (size_t)NUM_GRAPHS * 4, stream);
    hipMemsetAsync(sums, 0, (size_t)NUM_GRAPHS * HIDDEN * 4, stream);

    const int* srcp = ei;
    const int* dstp = ei + N_EDGES;

    // CSR + degree + graph buckets
    k_count<<<(N_EDGES + 255) / 256, 256, 0, stream>>>(dstp, cnt);
    k_count_batch<<<(N_NODES + 511) / 512, 512, 0, stream>>>(batch, gcnt);
    k_chunksum<<<NCHUNK, 256, 0, stream>>>(cnt, csum);
    k_scan2<<<2, 256, 0, stream>>>(csum, choff, gcnt, goff, gcur);
    k_apply<<<NCHUNK, 256, 0, stream>>>(cnt, choff, rowp, dinv, bincur);
    k_binA<<<(N_EDGES + 256 * FILLA_EPT - 1) / (256 * FILLA_EPT), 256, 0, stream>>>(
        srcp, dstp, bincur, pairs);
    k_binB<<<NBINS, 512, 0, stream>>>(pairs, rowp, col);
    k_fillg<<<(N_NODES + 511) / 512, 512, 0, stream>>>(batch, gcur, nlist);

    // weight repack (fp8, all 4 layers, one launch)
    k_repackAll<<<(8 * 8 * 64 + 3 * 8 * 16 * 64 + 255) / 256, 256, 0, stream>>>(
        W1, Wsp, Wp1, Wp2, Wp3, Wp4);

    const int GG = (N_NODES + 63) / 64;
    const int NB4 = (N_NODES + 3) / 4;

    // layer 1 (fp8 gather of x*dinv; fp8 A; fp8 output h1)
    k_prescale<<<(N_NODES * IN_FEAT / 4 + 255) / 256, 256, 0, stream>>>(x, dinv, p8);
    k_agg128<<<NB4, 256, 0, stream>>>(p8, col, rowp, dinv, a8);
    k_mgemm<IN_FEAT, 0><<<GG, 256, 0, stream>>>(a8, Wp1, b1, gamma, beta, rmean, rvar, dinv, h8);

    // layers 2..3 (fp8 gather; fp8 output)
    k_agg8<<<NB4, 256, 0, stream>>>(h8, col, rowp, dinv, a8);
    k_mgemm<HIDDEN, 1><<<GG, 256, 0, stream>>>(a8, Wp2, bsp + 0 * HIDDEN,
                                               nullptr, nullptr, nullptr, nullptr, dinv, h8);

    k_agg8<<<NB4, 256, 0, stream>>>(h8, col, rowp, dinv, a8);
    k_mgemm<HIDDEN, 1><<<GG, 256, 0, stream>>>(a8, Wp3, bsp + 1 * HIDDEN,
                                               nullptr, nullptr, nullptr, nullptr, dinv, h8);

    // layer 4 (plain relu; fp8 h4 feeds pooling)
    k_agg8<<<NB4, 256, 0, stream>>>(h8, col, rowp, dinv, a8);
    k_mgemm<HIDDEN, 2><<<GG, 256, 0, stream>>>(a8, Wp4, bsp + 2 * HIDDEN,
                                               nullptr, nullptr, nullptr, nullptr, dinv, h8);

    k_pool2<<<NUM_GRAPHS * 2 * 4, 256, 0, stream>>>(h8, nlist, goff, sums);
    k_logits<<<NUM_GRAPHS, 256, 0, stream>>>(sums, gcnt, W2, b2, out);
}